// Round 9
// baseline (243.808 us; speedup 1.0000x reference)
//
#include <hip/hip_runtime.h>
#include <hip/hip_bf16.h>
#include <stdint.h>

#define B_DIM 8192
#define D_DIM 2048
#define U_DIM 2048
#define KWORDS 64            // bit path: 2048 bits = 64 u32 words

typedef int v4i  __attribute__((ext_vector_type(4)));
typedef int v16i __attribute__((ext_vector_type(16)));

// Async global->LDS DMA, 16B per lane. LDS dest is wave-uniform base + lane*16;
// global src may be per-lane arbitrary.
__device__ __forceinline__ void load_lds16(const char* g, char* l) {
    __builtin_amdgcn_global_load_lds(
        (const __attribute__((address_space(1))) unsigned int*)g,
        (__attribute__((address_space(3))) unsigned int*)l,
        16, 0, 0);
}

// Counted vmem wait: never drain to 0 in the main loop (T4).
#define WAITVM(n) asm volatile("s_waitcnt vmcnt(" #n ")" ::: "memory")
// rule #18: inline-asm lgkmcnt(0) must be followed by sched_barrier(0)
#define LGKM0 do { asm volatile("s_waitcnt lgkmcnt(0)" ::: "memory"); \
                   __builtin_amdgcn_sched_barrier(0); } while (0)

// ======================= i8 MFMA PATH =======================

// x [B][D] f32 -> xi [B][D] i8 (+1/-1). float4 in, packed u32 out. Coalesced.
__global__ void pack_x_i8(const float* __restrict__ x, char* __restrict__ xi) {
    int idx = blockIdx.x * 256 + threadIdx.x;
    float4 v = ((const float4*)x)[idx];
    unsigned b0 = (v.x >= 0.f) ? 0x01u : 0xFFu;
    unsigned b1 = (v.y >= 0.f) ? 0x01u : 0xFFu;
    unsigned b2 = (v.z >= 0.f) ? 0x01u : 0xFFu;
    unsigned b3 = (v.w >= 0.f) ? 0x01u : 0xFFu;
    ((unsigned*)xi)[idx] = b0 | (b1 << 8) | (b2 << 16) | (b3 << 24);
}

// k [D][U] f32 -> kt [U][D] i8 (+1/-1), transposed via LDS 64x64 tile.
__global__ void pack_kt_i8(const float* __restrict__ k, char* __restrict__ kt) {
    __shared__ float tile[64][65];
    const int j0 = (blockIdx.x & 31) * 64;   // U tile
    const int d0 = (blockIdx.x >> 5) * 64;   // D tile
    const int tid = threadIdx.x;
    const int lane = tid & 63;
    const int wv = tid >> 6;
    for (int i = 0; i < 16; i++) {
        int row = i * 4 + wv;
        tile[row][lane] = k[(size_t)(d0 + row) * U_DIM + j0 + lane];
    }
    __syncthreads();
    const int u = tid >> 2;          // 0..63 output row (unit)
    const int g = tid & 3;           // 16-byte group along D
    union { char c[16]; int4 v; } pk;
#pragma unroll
    for (int j = 0; j < 16; j++)
        pk.c[j] = (tile[g * 16 + j][u] >= 0.f) ? (char)1 : (char)-1;
    *(int4*)(kt + (size_t)(j0 + u) * D_DIM + d0 + g * 16) = pk.v;
}

// out[i][j] = sum_k xi[i][k]*kt[j][k] + bias[j], exact in i32.
//
// R9: BARRIER-FREE, WAVE-PRIVATE pipeline. Eight prior structures (2-barrier,
// 1-barrier ring, phased, SGB-pinned, reg-dbuf, cross-block TLP) all landed
// at 45-58us / MfmaUtil 24-28% -> the stall is the shared invariant: the
// per-tile cross-wave certification chain (vmcnt -> s_barrier -> read) and
// barrier rendezvous. R9 removes it: each wave DMA-stages ITS OWN A/B slice
// into ITS OWN LDS region and reads only its own data. Per-wave vmcnt then
// certifies everything (the R7 cross-wave bug structurally cannot occur);
// the K-loop has ZERO barriers. Two free-running waves per SIMD destagger
// naturally (m114 overlap without barrier coupling).
//
// Geometry: 512 blocks of 256x128 (2 blocks/CU), 256 thr = 4 waves (2x2,
// wave tile 128x64, acc[4][2]=128 VGPR -> 2 waves/SIMD). BK=32B (one K=32
// MFMA step per tile, 64 tiles). Per-wave LDS: ring-3 x (A 4KB + B 2KB) =
// 18KB; block 72KB; 2 blocks = 144KB <= 160KB.
//
// LDS layout GROUP-MAJOR [g][row][16B] (g = K-halfgroup = lane>>5): both the
// DMA writes and the fragment reads are contiguous 512B segments -> bank-
// conflict-free, NO swizzle needed (prior rounds carried 2-3.1M conflict cy).
//
// Per wave per tile t:
//   WAITVM(12)  (own stage(t) landed; stage(t+1),(t+2) in flight ~1200cy
//                lookahead >> L2 latency)
//   6x ds_read_b128 (own region, buf t%3)
//   LGKM0       (reads retired -> licenses overwrite of buf t%3)
//   stage(t+3 -> buf t%3)   (6 DMA instrs, streams under MFMA)
//   8x mfma_i32_32x32x32_i8 (no waits: operands in regs)
// Epilogue peels t=61,62,63 draining vmcnt 12 -> 6 -> 0.
//
// XCD swizzle: 64 consecutive blocks per XCD.
__launch_bounds__(256, 2)
__global__ void gemm_i8(const char* __restrict__ xi,   // [8192][2048]
                        const char* __restrict__ kt,   // [2048][2048]
                        const float* __restrict__ bias,
                        float* __restrict__ out) {
    // [wave][ring][ A: slots 0..255 | B: slots 256..383 ]  (16B slots)
    __shared__ uint4 lds[4][3][384];   // 73728 B

    const int tid  = threadIdx.x;
    const int lane = tid & 63;
    const int w    = tid >> 6;       // 4 waves
    const int m    = lane & 31;
    const int half = lane >> 5;

    // XCD-aware swizzle (nwg=512, 8 XCDs, 64 blocks/chunk; bijective)
    const int bid = blockIdx.x;
    const int swz = ((bid & 7) << 6) | (bid >> 3);
    const int bx  = swz & 15;        // U tile index [0,16)
    const int by  = swz >> 4;        // B tile index [0,32)
    const int rows0 = by << 8;       // 256-row block
    const int cols0 = bx << 7;       // 128-col block

    const int wr = (w >> 1) << 7;    // wave row offset: 0 or 128
    const int wc = (w & 1) << 6;     // wave col offset: 0 or 64

    v16i acc[4][2];
#pragma unroll
    for (int mi = 0; mi < 4; ++mi)
#pragma unroll
        for (int nj = 0; nj < 2; ++nj)
#pragma unroll
            for (int i = 0; i < 16; ++i) acc[mi][nj][i] = 0;

    // wave-private global bases: 128 A-rows, 64 B-rows
    const char* aw = xi + (size_t)(rows0 + wr) * D_DIM;
    const char* bw = kt + (size_t)(cols0 + wc) * D_DIM;

    // staging source offsets (group-major dest):
    // A instr j (0..3): slot = j*64+lane; row = slot&127; g = slot>>7
    // B instr j (0..1): slot = j*64+lane; row = slot&63;  g = slot>>6
    size_t gA[4], gB[2];
#pragma unroll
    for (int j = 0; j < 4; ++j) {
        const int slot = j * 64 + lane;
        gA[j] = (size_t)(slot & 127) * D_DIM + (size_t)((slot >> 7) << 4);
    }
#pragma unroll
    for (int j = 0; j < 2; ++j) {
        const int slot = j * 64 + lane;
        gB[j] = (size_t)(slot & 63) * D_DIM + (size_t)((slot >> 6) << 4);
    }

    auto stage = [&](int t, int buf) {
        const size_t kof = (size_t)t << 5;       // t * 32 bytes along K
#pragma unroll
        for (int j = 0; j < 4; ++j)
            load_lds16(aw + gA[j] + kof, (char*)&lds[w][buf][j * 64]);
#pragma unroll
        for (int j = 0; j < 2; ++j)
            load_lds16(bw + gB[j] + kof, (char*)&lds[w][buf][256 + j * 64]);
    };

    // fragment read offsets (group-major, conflict-free):
    // A frag mi: slot = half*128 + mi*32 + m ; B frag nj: 256 + half*64 + nj*32 + m
    int aoff[4], boff[2];
#pragma unroll
    for (int mi = 0; mi < 4; ++mi) aoff[mi] = (half * 128 + mi * 32 + m) << 4;
#pragma unroll
    for (int nj = 0; nj < 2; ++nj) boff[nj] = (256 + half * 64 + nj * 32 + m) << 4;

    // prologue: stage tiles 0,1,2 (18 own loads in flight)
    stage(0, 0); stage(1, 1); stage(2, 2);

    int cb = 0;                       // t % 3
#pragma unroll 1
    for (int t = 0; t < 61; ++t) {
        WAITVM(12);                   // own tile-t loads landed
        const char* Ls = (const char*)lds[w][cb];
        v4i a0 = *(const v4i*)(Ls + aoff[0]);
        v4i a1 = *(const v4i*)(Ls + aoff[1]);
        v4i a2 = *(const v4i*)(Ls + aoff[2]);
        v4i a3 = *(const v4i*)(Ls + aoff[3]);
        v4i b0 = *(const v4i*)(Ls + boff[0]);
        v4i b1 = *(const v4i*)(Ls + boff[1]);
        LGKM0;                        // reads retired -> buf cb reusable
        stage(t + 3, cb);             // overwrite own buf (ring-3)
        acc[0][0] = __builtin_amdgcn_mfma_i32_32x32x32_i8(a0, b0, acc[0][0], 0, 0, 0);
        acc[0][1] = __builtin_amdgcn_mfma_i32_32x32x32_i8(a0, b1, acc[0][1], 0, 0, 0);
        acc[1][0] = __builtin_amdgcn_mfma_i32_32x32x32_i8(a1, b0, acc[1][0], 0, 0, 0);
        acc[1][1] = __builtin_amdgcn_mfma_i32_32x32x32_i8(a1, b1, acc[1][1], 0, 0, 0);
        acc[2][0] = __builtin_amdgcn_mfma_i32_32x32x32_i8(a2, b0, acc[2][0], 0, 0, 0);
        acc[2][1] = __builtin_amdgcn_mfma_i32_32x32x32_i8(a2, b1, acc[2][1], 0, 0, 0);
        acc[3][0] = __builtin_amdgcn_mfma_i32_32x32x32_i8(a3, b0, acc[3][0], 0, 0, 0);
        acc[3][1] = __builtin_amdgcn_mfma_i32_32x32x32_i8(a3, b1, acc[3][1], 0, 0, 0);
        cb = (cb == 2) ? 0 : cb + 1;
    }
    // peeled t=61 (buf 1), 62 (buf 2), 63 (buf 0): drain 12 -> 6 -> 0
#pragma unroll
    for (int p = 0; p < 3; ++p) {
        if (p == 0) { WAITVM(12); }
        else if (p == 1) { WAITVM(6); }
        else { WAITVM(0); }
        const int buf = (p == 0) ? 1 : (p == 1) ? 2 : 0;
        const char* Ls = (const char*)lds[w][buf];
        v4i a0 = *(const v4i*)(Ls + aoff[0]);
        v4i a1 = *(const v4i*)(Ls + aoff[1]);
        v4i a2 = *(const v4i*)(Ls + aoff[2]);
        v4i a3 = *(const v4i*)(Ls + aoff[3]);
        v4i b0 = *(const v4i*)(Ls + boff[0]);
        v4i b1 = *(const v4i*)(Ls + boff[1]);
        LGKM0;
        acc[0][0] = __builtin_amdgcn_mfma_i32_32x32x32_i8(a0, b0, acc[0][0], 0, 0, 0);
        acc[0][1] = __builtin_amdgcn_mfma_i32_32x32x32_i8(a0, b1, acc[0][1], 0, 0, 0);
        acc[1][0] = __builtin_amdgcn_mfma_i32_32x32x32_i8(a1, b0, acc[1][0], 0, 0, 0);
        acc[1][1] = __builtin_amdgcn_mfma_i32_32x32x32_i8(a1, b1, acc[1][1], 0, 0, 0);
        acc[2][0] = __builtin_amdgcn_mfma_i32_32x32x32_i8(a2, b0, acc[2][0], 0, 0, 0);
        acc[2][1] = __builtin_amdgcn_mfma_i32_32x32x32_i8(a2, b1, acc[2][1], 0, 0, 0);
        acc[3][0] = __builtin_amdgcn_mfma_i32_32x32x32_i8(a3, b0, acc[3][0], 0, 0, 0);
        acc[3][1] = __builtin_amdgcn_mfma_i32_32x32x32_i8(a3, b1, acc[3][1], 0, 0, 0);
    }

    // C/D 32x32 layout (HW-verified): col = lane&31, row = (reg&3)+8*(reg>>2)+4*half
#pragma unroll
    for (int mi = 0; mi < 4; ++mi)
#pragma unroll
        for (int nj = 0; nj < 2; ++nj) {
            const int n = cols0 + wc + nj * 32 + m;
            const float bb = bias[n];
#pragma unroll
            for (int reg = 0; reg < 16; ++reg) {
                const int row = (reg & 3) + 8 * (reg >> 2) + 4 * half;
                const size_t grow = (size_t)(rows0 + wr + mi * 32 + row);
                out[grow * U_DIM + n] = (float)acc[mi][nj][reg] + bb;
            }
        }
}

// ======================= BIT-PATH FALLBACK (R5, proven) =======================

__global__ void pack_x_kernel(const float* __restrict__ x,
                              unsigned long long* __restrict__ xb) {
    const int gwave = (blockIdx.x * blockDim.x + threadIdx.x) >> 6;
    const int lane  = threadIdx.x & 63;
    const size_t base = (size_t)gwave * 256;
    float v0 = x[base + lane];
    float v1 = x[base + 64 + lane];
    float v2 = x[base + 128 + lane];
    float v3 = x[base + 192 + lane];
    unsigned long long m0 = __ballot(v0 >= 0.0f);
    unsigned long long m1 = __ballot(v1 >= 0.0f);
    unsigned long long m2 = __ballot(v2 >= 0.0f);
    unsigned long long m3 = __ballot(v3 >= 0.0f);
    if (lane == 0) {
        ulonglong2* p = (ulonglong2*)(xb + (base >> 6));
        ulonglong2 a; a.x = m0; a.y = m1;
        ulonglong2 b; b.x = m2; b.y = m3;
        p[0] = a;
        p[1] = b;
    }
}

__global__ void pack_k_kernel(const float* __restrict__ k,
                              unsigned long long* __restrict__ kb) {
    __shared__ float tile[64][65];
    const int j0 = (blockIdx.x & 31) * 64;
    const int d0 = (blockIdx.x >> 5) * 64;
    const int tid  = threadIdx.x;
    const int lane = tid & 63;
    const int wv   = tid >> 6;
    for (int i = 0; i < 16; i++) {
        int row = i * 4 + wv;
        tile[row][lane] = k[(size_t)(d0 + row) * U_DIM + j0 + lane];
    }
    __syncthreads();
    for (int c = wv * 16; c < wv * 16 + 16; c++) {
        float v = tile[lane][c];
        unsigned long long m = __ballot(v >= 0.0f);
        if (lane == 0) kb[(size_t)(j0 + c) * (D_DIM / 64) + (d0 >> 6)] = m;
    }
}

__launch_bounds__(512)
__global__ void bgemm_kernel(const unsigned int* __restrict__ xb,
                             const unsigned int* __restrict__ kb,
                             const float* __restrict__ bias,
                             float* __restrict__ out) {
    __shared__ unsigned int xs[128 * KWORDS];
    __shared__ unsigned int ks[128 * KWORDS];
    const int bx  = blockIdx.x;
    const int by  = blockIdx.y;
    const int tid = threadIdx.x;
    const uint4* xsrc = (const uint4*)(xb + (size_t)(by * 128) * KWORDS);
    const uint4* ksrc = (const uint4*)(kb + (size_t)(bx * 128) * KWORDS);
#pragma unroll
    for (int i = 0; i < 4; i++) {
        int flat = tid + i * 512;
        int r    = flat >> 4;
        int g    = flat & 15;
        int sg   = g ^ ((r >> 3) & 7);
        uint4 xv = xsrc[flat];
        uint4 kv = ksrc[flat];
        *((uint4*)&xs[r * KWORDS + sg * 4]) = xv;
        *((uint4*)&ks[r * KWORDS + sg * 4]) = kv;
    }
    __syncthreads();
    const int tr   = (tid >> 4) * 4;
    const int tc   = (tid & 15) * 8;
    const int xswz = ((tid >> 4) >> 1) & 7;
    const int ksw  = tid & 7;
    int acc[4][8] = {};
    for (int w4 = 0; w4 < 16; w4++) {
        const int xcol = (w4 ^ xswz) * 4;
        const int kcol = (w4 ^ ksw) * 4;
        uint4 xv[4], kv[8];
#pragma unroll
        for (int r = 0; r < 4; r++) xv[r] = *((const uint4*)&xs[(tr + r) * KWORDS + xcol]);
#pragma unroll
        for (int c = 0; c < 8; c++) kv[c] = *((const uint4*)&ks[(tc + c) * KWORDS + kcol]);
#pragma unroll
        for (int r = 0; r < 4; r++)
#pragma unroll
            for (int c = 0; c < 8; c++) {
                acc[r][c] += __popc(xv[r].x ^ kv[c].x);
                acc[r][c] += __popc(xv[r].y ^ kv[c].y);
                acc[r][c] += __popc(xv[r].z ^ kv[c].z);
                acc[r][c] += __popc(xv[r].w ^ kv[c].w);
            }
    }
    const int row0 = by * 128 + tr;
    const int col0 = bx * 128 + tc;
    const float4 b0 = *((const float4*)&bias[col0]);
    const float4 b1 = *((const float4*)&bias[col0 + 4]);
#pragma unroll
    for (int r = 0; r < 4; r++) {
        float4 o0, o1;
        o0.x = (float)(D_DIM - 2 * acc[r][0]) + b0.x;
        o0.y = (float)(D_DIM - 2 * acc[r][1]) + b0.y;
        o0.z = (float)(D_DIM - 2 * acc[r][2]) + b0.z;
        o0.w = (float)(D_DIM - 2 * acc[r][3]) + b0.w;
        o1.x = (float)(D_DIM - 2 * acc[r][4]) + b1.x;
        o1.y = (float)(D_DIM - 2 * acc[r][5]) + b1.y;
        o1.z = (float)(D_DIM - 2 * acc[r][6]) + b1.z;
        o1.w = (float)(D_DIM - 2 * acc[r][7]) + b1.w;
        float* orow = &out[(size_t)(row0 + r) * U_DIM + col0];
        *((float4*)orow)       = o0;
        *((float4*)(orow + 4)) = o1;
    }
}

// ======================= launcher =======================

extern "C" void kernel_launch(void* const* d_in, const int* in_sizes, int n_in,
                              void* d_out, int out_size, void* d_ws, size_t ws_size,
                              hipStream_t stream) {
    const float* x    = (const float*)d_in[0];   // [8192][2048]
    const float* k    = (const float*)d_in[1];   // [2048][2048]
    const float* bias = (const float*)d_in[2];   // [2048]
    float* out = (float*)d_out;

    const size_t need_i8 = (size_t)B_DIM * D_DIM + (size_t)U_DIM * D_DIM; // ~21 MB
    if (ws_size >= need_i8) {
        char* xi = (char*)d_ws;                          // 16 MB
        char* kt = xi + (size_t)B_DIM * D_DIM;           // 4 MB
        pack_x_i8<<<(B_DIM * D_DIM) / 1024, 256, 0, stream>>>(x, xi);
        pack_kt_i8<<<32 * 32, 256, 0, stream>>>(k, kt);
        gemm_i8<<<512, 256, 0, stream>>>(xi, kt, bias, out);
    } else {
        unsigned long long* xbits = (unsigned long long*)d_ws;
        unsigned long long* kbits = (unsigned long long*)((char*)d_ws + (size_t)B_DIM * (D_DIM / 8));
        pack_x_kernel<<<(B_DIM * D_DIM) / 1024, 256, 0, stream>>>(x, xbits);
        pack_k_kernel<<<32 * 32, 256, 0, stream>>>(k, kbits);
        dim3 grid(U_DIM / 128, B_DIM / 128);
        bgemm_kernel<<<grid, 512, 0, stream>>>((const unsigned int*)xbits,
                                               (const unsigned int*)kbits, bias, out);
    }
}

// Round 10
// 144.721 us; speedup vs baseline: 1.6847x; 1.6847x over previous
//
#include <hip/hip_runtime.h>
#include <hip/hip_bf16.h>
#include <stdint.h>

#define B_DIM 8192
#define D_DIM 2048
#define U_DIM 2048
#define DB    1024           // packed fp4 row stride in bytes (2048 elems / 2)
#define KWORDS 64            // bit path: 2048 bits = 64 u32 words

typedef int   v4i  __attribute__((ext_vector_type(4)));
typedef int   v8i  __attribute__((ext_vector_type(8)));
typedef float v16f __attribute__((ext_vector_type(16)));

// Async global->LDS DMA, 16B per lane. LDS dest is wave-uniform base + lane*16;
// global src may be per-lane arbitrary (we fold the bank swizzle there).
__device__ __forceinline__ void load_lds16(const char* g, char* l) {
    __builtin_amdgcn_global_load_lds(
        (const __attribute__((address_space(1))) unsigned int*)g,
        (__attribute__((address_space(3))) unsigned int*)l,
        16, 0, 0);
}

// Counted vmem wait: never drain to 0 in the main loop (T4).
#define WAITVM(n) asm volatile("s_waitcnt vmcnt(" #n ")" ::: "memory")
#define SBAR      __builtin_amdgcn_s_barrier()
#define SCHED0    __builtin_amdgcn_sched_barrier(0)
// rule #18: lgkmcnt(0) via inline asm must be followed by sched_barrier(0)
#define LGKM0     do { asm volatile("s_waitcnt lgkmcnt(0)" ::: "memory"); SCHED0; } while (0)

// ======================= MX-FP4 MFMA PATH =======================
// ste_sign values are exactly representable in fp4 e2m1: +1.0 = 0x2, -1.0 = 0xA.
// Products are +/-1, accumulated exactly in f32 (|sum| <= 2048 << 2^24).
// mfma_scale_f32_32x32x64_f8f6f4 with FMT=fp4 (cbsz=blgp=4) and unit E8M0
// scales (0x7F = 2^0) runs at ~9099 TOPS (2.07x the i8 ceiling) with K=64.

// x [B][D] f32 -> xq [B][D/2] fp4-packed. float4 in (16B/lane coalesced),
// ushort out (2B/lane, contiguous 128B/wave).
__global__ void pack_x_fp4(const float* __restrict__ x, unsigned short* __restrict__ xq) {
    int idx = blockIdx.x * 256 + threadIdx.x;   // float4 index
    float4 v = ((const float4*)x)[idx];
    unsigned n0 = (v.x >= 0.f) ? 0x2u : 0xAu;
    unsigned n1 = (v.y >= 0.f) ? 0x2u : 0xAu;
    unsigned n2 = (v.z >= 0.f) ? 0x2u : 0xAu;
    unsigned n3 = (v.w >= 0.f) ? 0x2u : 0xAu;
    xq[idx] = (unsigned short)(n0 | (n1 << 4) | (n2 << 8) | (n3 << 12));
}

// k [D][U] f32 -> ktq [U][D/2] fp4-packed, transposed via LDS 64x64 tile.
__global__ void pack_kt_fp4(const float* __restrict__ k, unsigned char* __restrict__ ktq) {
    __shared__ float tile[64][65];
    const int j0 = (blockIdx.x & 31) * 64;   // U tile
    const int d0 = (blockIdx.x >> 5) * 64;   // D tile
    const int tid = threadIdx.x;
    const int lane = tid & 63;
    const int wv = tid >> 6;
    for (int i = 0; i < 16; i++) {
        int row = i * 4 + wv;
        tile[row][lane] = k[(size_t)(d0 + row) * U_DIM + j0 + lane];
    }
    __syncthreads();
    const int u = tid >> 2;          // 0..63 output row (unit)
    const int q = tid & 3;           // 8-byte group along D (16 elems)
    unsigned long long ob = 0ull;
#pragma unroll
    for (int jj = 0; jj < 8; ++jj) {
        float lo = tile[q * 16 + 2 * jj][u];
        float hi = tile[q * 16 + 2 * jj + 1][u];
        unsigned byte = ((lo >= 0.f) ? 0x2u : 0xAu) | (((hi >= 0.f) ? 0x2u : 0xAu) << 4);
        ob |= (unsigned long long)byte << (8 * jj);
    }
    *(unsigned long long*)(ktq + (size_t)(j0 + u) * DB + (d0 >> 1) + q * 8) = ob;
}

// out[i][j] = sum_k sign(x)*sign(k) + bias[j], exact in f32 via fp4 MFMA.
//
// R10: dtype lever. Nine schedule variants all converged to ~2650 cy/tile
// (DS+MFMA serialized + overhead) - the per-tile cost is structural for this
// phase pattern. So halve the TILE COUNT and the per-op cost: MX-fp4 doubles
// MFMA throughput (9099 vs 4404 TOPS) and halves staging bytes. The schedule
// below is BYTE-IDENTICAL to R3 (the measured-best 45.6us structure): same
// 64B rows, same slot/swizzle math, same 2-phase barriers and counted vmcnt -
// only row stride (2048->1024), NT (32->16), and the MFMA opcode change.
// Per K-tile (BK=128 fp4 elems = 64B/row): per wave 12 ds_read_b128 +
// 16 mfma_scale_f32_32x32x64_f8f6f4 (K=64 each) - same instruction counts
// per tile as R3, half as many tiles.
//
// Bank swizzle folded into the GLOBAL source (LDS dest stays linear for
// global_load_lds): within each 128B row-pair, 16B slot s <- s ^ (pair&7).
// Grid = 256 blocks = 1/CU; XCD swizzle: contiguous 32-block chunk per XCD.
__launch_bounds__(512, 2)
__global__ void gemm_fp4(const char* __restrict__ xq,   // [8192][1024]
                         const char* __restrict__ ktq,  // [2048][1024]
                         const float* __restrict__ bias,
                         float* __restrict__ out) {
    __shared__ uint4 lds[4][2048];   // [buf][ A:slots 0..1023 | B:1024..2047 ]

    const int tid  = threadIdx.x;
    const int lane = tid & 63;
    const int w    = tid >> 6;       // 8 waves
    const int m    = lane & 31;
    const int half = lane >> 5;

    // XCD-aware swizzle (nwg=256, 8 XCDs, 32 blocks/chunk; bijective)
    const int bid = blockIdx.x;
    const int swz = ((bid & 7) << 5) | (bid >> 3);
    const int bx  = swz & 7;         // U tile index [0,8)
    const int by  = swz >> 3;        // B tile index [0,32)
    const int rows0 = by << 8;
    const int cols0 = bx << 8;

    const int wr = (w >> 2) << 7;    // wave row offset: 0 or 128
    const int wc = (w & 3) << 6;     // wave col offset: 0/64/128/192

    v16f acc[4][2];
#pragma unroll
    for (int mi = 0; mi < 4; ++mi)
#pragma unroll
        for (int nj = 0; nj < 2; ++nj)
#pragma unroll
            for (int i = 0; i < 16; ++i) acc[mi][nj][i] = 0.0f;

    const char* abase = xq  + (size_t)rows0 * DB;
    const char* bbase = ktq + (size_t)cols0 * DB;

    // --- staging precompute: 2 A-slots + 2 B-slots per thread ---
    // flat slot s in [0,1024): row = s>>2, g = s&3 (16B groups of 64B rows).
    // Storage slot (p=row>>1, sp=((row&1)<<2)|g) holds global slot
    // sl = sp ^ (p&7) -> row/group (swizzle folded into global source).
    int   sbase[2];
    size_t goff0[2];
#pragma unroll
    for (int j = 0; j < 2; ++j) {
        sbase[j] = (w << 6) + (j << 9);          // wave-uniform LDS slot base
        const int s   = sbase[j] + lane;
        const int row = s >> 2, g = s & 3;
        const int p   = row >> 1;
        const int sl  = ((((row & 1) << 2) | g) ^ (p & 7));
        const int gr  = (p << 1) | (sl >> 2);
        const int gg  = sl & 3;
        goff0[j] = (size_t)gr * DB + (size_t)(gg << 4);
    }

    auto stageA = [&](int t, int buf) {
        const size_t kof = (size_t)t << 6;       // t * 64 bytes along K
#pragma unroll
        for (int j = 0; j < 2; ++j)
            load_lds16(abase + goff0[j] + kof, (char*)&lds[buf][sbase[j]]);
    };
    auto stageB = [&](int t, int buf) {
        const size_t kof = (size_t)t << 6;
#pragma unroll
        for (int j = 0; j < 2; ++j)
            load_lds16(bbase + goff0[j] + kof, (char*)&lds[buf][1024 + sbase[j]]);
    };

    // --- fragment read offsets (loop-invariant; swizzled) ---
    // logical: row rl, 16B group gl = kk*2+half -> byte (rl>>1)*128 + st*16
    // (group gl = K-subblock: MFMA kk covers k in [kk*64,kk*64+64); lane half
    //  covers 32 elems = 16B. A/B use identical k-layouts -> any within-lane
    //  permutation cancels in the dot product.)
    int aoff[4][2], boff[2][2];
#pragma unroll
    for (int mi = 0; mi < 4; ++mi)
#pragma unroll
        for (int kk = 0; kk < 2; ++kk) {
            const int rl = wr + mi * 32 + m;
            const int gl = kk * 2 + half;
            const int p  = rl >> 1;
            const int st = ((((rl & 1) << 2) | gl) ^ (p & 7));
            aoff[mi][kk] = (p << 7) + (st << 4);
        }
#pragma unroll
    for (int nj = 0; nj < 2; ++nj)
#pragma unroll
        for (int kk = 0; kk < 2; ++kk) {
            const int rl = wc + nj * 32 + m;
            const int gl = kk * 2 + half;
            const int p  = rl >> 1;
            const int st = ((((rl & 1) << 2) | gl) ^ (p & 7));
            boff[nj][kk] = 16384 + (p << 7) + (st << 4);
        }

    // fp4 operands occupy the LOW 4 regs of the v8i MFMA operand.
    typedef union { v8i v8; v4i v4[2]; } opnd_t;

    auto phaseReads = [&](const char* Ls, int kk, opnd_t af[4], opnd_t bf[2]) {
#pragma unroll
        for (int mi = 0; mi < 4; ++mi) {
            af[mi].v4[1] = (v4i){0, 0, 0, 0};
            af[mi].v4[0] = *(const v4i*)(Ls + aoff[mi][kk]);
        }
#pragma unroll
        for (int nj = 0; nj < 2; ++nj) {
            bf[nj].v4[1] = (v4i){0, 0, 0, 0};
            bf[nj].v4[0] = *(const v4i*)(Ls + boff[nj][kk]);
        }
    };
    auto phaseMMA = [&](opnd_t af[4], opnd_t bf[2]) {
        __builtin_amdgcn_s_setprio(1);
#pragma unroll
        for (int mi = 0; mi < 4; ++mi)
#pragma unroll
            for (int nj = 0; nj < 2; ++nj)
                acc[mi][nj] = __builtin_amdgcn_mfma_scale_f32_32x32x64_f8f6f4(
                    af[mi].v8, bf[nj].v8, acc[mi][nj],
                    4, 4,                       // cbsz=FP4, blgp=FP4
                    0, 0x7F7F7F7Fu,             // scale_a = 1.0 (E8M0 127)
                    0, 0x7F7F7F7Fu);            // scale_b = 1.0
        __builtin_amdgcn_s_setprio(0);
    };

    // prologue: stage tiles 0,1,2 (12 loads/thread in flight)
    stageA(0, 0); stageB(0, 0);
    stageA(1, 1); stageB(1, 1);
    stageA(2, 2); stageB(2, 2);
    WAITVM(8);                        // tile 0 landed (own)
    SBAR;                             // ... chip-wide

    // main loop: tiles 0..12; stage tile t+3 into buf[(t+3)&3]
#pragma unroll 1
    for (int t = 0; t < 13; ++t) {
        const char* Ls = (const char*)lds[t & 3];
        const int nb = (t + 3) & 3;
        opnd_t af[4], bf[2];
        // ---- phase A (kk=0) ----
        phaseReads(Ls, 0, af, bf);
        stageA(t + 3, nb);
        SCHED0; SBAR; LGKM0;
        phaseMMA(af, bf);
        SBAR;
        // ---- phase B (kk=1) ----
        phaseReads(Ls, 1, af, bf);
        stageB(t + 3, nb);
        WAITVM(8);                    // tile t+1 landed (own); barrier -> all
        SCHED0; SBAR; LGKM0;
        phaseMMA(af, bf);
        SBAR;
    }
    // peeled t=13 (buf 1): no staging; drain 8 -> 4
    {
        const char* Ls = (const char*)lds[1];
        opnd_t af[4], bf[2];
        phaseReads(Ls, 0, af, bf);
        SCHED0; SBAR; LGKM0; phaseMMA(af, bf); SBAR;
        phaseReads(Ls, 1, af, bf);
        WAITVM(4);                    // tile 14 landed
        SCHED0; SBAR; LGKM0; phaseMMA(af, bf); SBAR;
    }
    // peeled t=14 (buf 2): drain 4 -> 0
    {
        const char* Ls = (const char*)lds[2];
        opnd_t af[4], bf[2];
        phaseReads(Ls, 0, af, bf);
        SCHED0; SBAR; LGKM0; phaseMMA(af, bf); SBAR;
        phaseReads(Ls, 1, af, bf);
        WAITVM(0);                    // tile 15 landed
        SCHED0; SBAR; LGKM0; phaseMMA(af, bf); SBAR;
    }
    // peeled t=15 (buf 3): everything resident
    {
        const char* Ls = (const char*)lds[3];
        opnd_t af[4], bf[2];
        phaseReads(Ls, 0, af, bf);
        phaseMMA(af, bf);
        phaseReads(Ls, 1, af, bf);
        phaseMMA(af, bf);
    }

    // C/D 32x32 layout (HW-verified, shape-determined not dtype-determined):
    // col = lane&31, row = (reg&3)+8*(reg>>2)+4*half. acc is already f32.
#pragma unroll
    for (int mi = 0; mi < 4; ++mi)
#pragma unroll
        for (int nj = 0; nj < 2; ++nj) {
            const int n = cols0 + wc + nj * 32 + m;
            const float bb = bias[n];
#pragma unroll
            for (int reg = 0; reg < 16; ++reg) {
                const int row = (reg & 3) + 8 * (reg >> 2) + 4 * half;
                const size_t grow = (size_t)(rows0 + wr + mi * 32 + row);
                out[grow * U_DIM + n] = acc[mi][nj][reg] + bb;
            }
        }
}

// ======================= BIT-PATH FALLBACK (R5, proven) =======================

__global__ void pack_x_kernel(const float* __restrict__ x,
                              unsigned long long* __restrict__ xb) {
    const int gwave = (blockIdx.x * blockDim.x + threadIdx.x) >> 6;
    const int lane  = threadIdx.x & 63;
    const size_t base = (size_t)gwave * 256;
    float v0 = x[base + lane];
    float v1 = x[base + 64 + lane];
    float v2 = x[base + 128 + lane];
    float v3 = x[base + 192 + lane];
    unsigned long long m0 = __ballot(v0 >= 0.0f);
    unsigned long long m1 = __ballot(v1 >= 0.0f);
    unsigned long long m2 = __ballot(v2 >= 0.0f);
    unsigned long long m3 = __ballot(v3 >= 0.0f);
    if (lane == 0) {
        ulonglong2* p = (ulonglong2*)(xb + (base >> 6));
        ulonglong2 a; a.x = m0; a.y = m1;
        ulonglong2 b; b.x = m2; b.y = m3;
        p[0] = a;
        p[1] = b;
    }
}

__global__ void pack_k_kernel(const float* __restrict__ k,
                              unsigned long long* __restrict__ kb) {
    __shared__ float tile[64][65];
    const int j0 = (blockIdx.x & 31) * 64;
    const int d0 = (blockIdx.x >> 5) * 64;
    const int tid  = threadIdx.x;
    const int lane = tid & 63;
    const int wv   = tid >> 6;
    for (int i = 0; i < 16; i++) {
        int row = i * 4 + wv;
        tile[row][lane] = k[(size_t)(d0 + row) * U_DIM + j0 + lane];
    }
    __syncthreads();
    for (int c = wv * 16; c < wv * 16 + 16; c++) {
        float v = tile[lane][c];
        unsigned long long m = __ballot(v >= 0.0f);
        if (lane == 0) kb[(size_t)(j0 + c) * (D_DIM / 64) + (d0 >> 6)] = m;
    }
}

__launch_bounds__(512)
__global__ void bgemm_kernel(const unsigned int* __restrict__ xb,
                             const unsigned int* __restrict__ kb,
                             const float* __restrict__ bias,
                             float* __restrict__ out) {
    __shared__ unsigned int xs[128 * KWORDS];
    __shared__ unsigned int ks[128 * KWORDS];
    const int bx  = blockIdx.x;
    const int by  = blockIdx.y;
    const int tid = threadIdx.x;
    const uint4* xsrc = (const uint4*)(xb + (size_t)(by * 128) * KWORDS);
    const uint4* ksrc = (const uint4*)(kb + (size_t)(bx * 128) * KWORDS);
#pragma unroll
    for (int i = 0; i < 4; i++) {
        int flat = tid + i * 512;
        int r    = flat >> 4;
        int g    = flat & 15;
        int sg   = g ^ ((r >> 3) & 7);
        uint4 xv = xsrc[flat];
        uint4 kv = ksrc[flat];
        *((uint4*)&xs[r * KWORDS + sg * 4]) = xv;
        *((uint4*)&ks[r * KWORDS + sg * 4]) = kv;
    }
    __syncthreads();
    const int tr   = (tid >> 4) * 4;
    const int tc   = (tid & 15) * 8;
    const int xswz = ((tid >> 4) >> 1) & 7;
    const int ksw  = tid & 7;
    int acc[4][8] = {};
    for (int w4 = 0; w4 < 16; w4++) {
        const int xcol = (w4 ^ xswz) * 4;
        const int kcol = (w4 ^ ksw) * 4;
        uint4 xv[4], kv[8];
#pragma unroll
        for (int r = 0; r < 4; r++) xv[r] = *((const uint4*)&xs[(tr + r) * KWORDS + xcol]);
#pragma unroll
        for (int c = 0; c < 8; c++) kv[c] = *((const uint4*)&ks[(tc + c) * KWORDS + kcol]);
#pragma unroll
        for (int r = 0; r < 4; r++)
#pragma unroll
            for (int c = 0; c < 8; c++) {
                acc[r][c] += __popc(xv[r].x ^ kv[c].x);
                acc[r][c] += __popc(xv[r].y ^ kv[c].y);
                acc[r][c] += __popc(xv[r].z ^ kv[c].z);
                acc[r][c] += __popc(xv[r].w ^ kv[c].w);
            }
    }
    const int row0 = by * 128 + tr;
    const int col0 = bx * 128 + tc;
    const float4 b0 = *((const float4*)&bias[col0]);
    const float4 b1 = *((const float4*)&bias[col0 + 4]);
#pragma unroll
    for (int r = 0; r < 4; r++) {
        float4 o0, o1;
        o0.x = (float)(D_DIM - 2 * acc[r][0]) + b0.x;
        o0.y = (float)(D_DIM - 2 * acc[r][1]) + b0.y;
        o0.z = (float)(D_DIM - 2 * acc[r][2]) + b0.z;
        o0.w = (float)(D_DIM - 2 * acc[r][3]) + b0.w;
        o1.x = (float)(D_DIM - 2 * acc[r][4]) + b1.x;
        o1.y = (float)(D_DIM - 2 * acc[r][5]) + b1.y;
        o1.z = (float)(D_DIM - 2 * acc[r][6]) + b1.z;
        o1.w = (float)(D_DIM - 2 * acc[r][7]) + b1.w;
        float* orow = &out[(size_t)(row0 + r) * U_DIM + col0];
        *((float4*)orow)       = o0;
        *((float4*)(orow + 4)) = o1;
    }
}

// ======================= launcher =======================

extern "C" void kernel_launch(void* const* d_in, const int* in_sizes, int n_in,
                              void* d_out, int out_size, void* d_ws, size_t ws_size,
                              hipStream_t stream) {
    const float* x    = (const float*)d_in[0];   // [8192][2048]
    const float* k    = (const float*)d_in[1];   // [2048][2048]
    const float* bias = (const float*)d_in[2];   // [2048]
    float* out = (float*)d_out;

    const size_t need_fp4 = (size_t)B_DIM * DB + (size_t)U_DIM * DB; // ~10 MB
    if (ws_size >= need_fp4) {
        unsigned short* xq = (unsigned short*)d_ws;                  // 8 MB
        unsigned char*  ktq = (unsigned char*)d_ws + (size_t)B_DIM * DB; // 2 MB
        pack_x_fp4<<<(B_DIM * D_DIM) / 1024, 256, 0, stream>>>(x, xq);
        pack_kt_fp4<<<32 * 32, 256, 0, stream>>>(k, ktq);
        gemm_fp4<<<256, 512, 0, stream>>>((const char*)xq, (const char*)ktq, bias, out);
    } else {
        unsigned long long* xbits = (unsigned long long*)d_ws;
        unsigned long long* kbits = (unsigned long long*)((char*)d_ws + (size_t)B_DIM * (D_DIM / 8));
        pack_x_kernel<<<(B_DIM * D_DIM) / 1024, 256, 0, stream>>>(x, xbits);
        pack_k_kernel<<<32 * 32, 256, 0, stream>>>(k, kbits);
        dim3 grid(U_DIM / 128, B_DIM / 128);
        bgemm_kernel<<<grid, 512, 0, stream>>>((const unsigned int*)xbits,
                                               (const unsigned int*)kbits, bias, out);
    }
}

// Round 11
// 142.785 us; speedup vs baseline: 1.7075x; 1.0136x over previous
//
#include <hip/hip_runtime.h>
#include <hip/hip_bf16.h>
#include <stdint.h>

#define B_DIM 8192
#define D_DIM 2048
#define U_DIM 2048
#define DB    1024           // packed fp4 row stride in bytes (2048 elems / 2)
#define KWORDS 64            // bit path: 2048 bits = 64 u32 words

typedef int   v4i  __attribute__((ext_vector_type(4)));
typedef int   v8i  __attribute__((ext_vector_type(8)));
typedef float v16f __attribute__((ext_vector_type(16)));

// Async global->LDS DMA, 16B per lane. LDS dest is wave-uniform base + lane*16;
// global src may be per-lane arbitrary (we fold the bank swizzle there).
__device__ __forceinline__ void load_lds16(const char* g, char* l) {
    __builtin_amdgcn_global_load_lds(
        (const __attribute__((address_space(1))) unsigned int*)g,
        (__attribute__((address_space(3))) unsigned int*)l,
        16, 0, 0);
}

// Counted vmem wait: never drain to 0 in the main loop (T4).
#define WAITVM(n) asm volatile("s_waitcnt vmcnt(" #n ")" ::: "memory")
#define SBAR      __builtin_amdgcn_s_barrier()
#define SCHED0    __builtin_amdgcn_sched_barrier(0)
// rule #18: lgkmcnt(0) via inline asm must be followed by sched_barrier(0)
#define LGKM0     do { asm volatile("s_waitcnt lgkmcnt(0)" ::: "memory"); SCHED0; } while (0)

// ======================= MX-FP4 MFMA PATH =======================
// ste_sign values are exactly representable in fp4 e2m1: +1.0 = 0x2, -1.0 = 0xA.
// Products are +/-1, accumulated exactly in f32 (|sum| <= 2048 << 2^24).
// mfma_scale_f32_32x32x64_f8f6f4 with FMT=fp4 (cbsz=blgp=4) and unit E8M0
// scales (0x7F = 2^0) runs at ~9099 TOPS (2.07x the i8 ceiling) with K=64.

// R11: SINGLE pack dispatch. Blocks [0,1024) transpose-pack k (LDS path);
// blocks [1024, 1024+16384) pack x (pure streaming). Saves one launch gap
// (~10us) and hides pack_kt (~3.5us) entirely under pack_x's 64MB read.
// Block-uniform divergence; 16.6KB LDS caps occupancy at 8 blocks/CU =
// 32 waves/CU (the hardware max) -> no BW loss on the x path.
__global__ void pack_fp4(const float* __restrict__ x,
                         const float* __restrict__ k,
                         unsigned short* __restrict__ xq,
                         unsigned char* __restrict__ ktq) {
    __shared__ float tile[64][65];
    const int tid = threadIdx.x;

    if (blockIdx.x >= 1024) {
        // ---- x path: [B][D] f32 -> [B][D/2] fp4. float4 in, ushort out. ----
        int idx = (blockIdx.x - 1024) * 256 + tid;   // float4 index
        float4 v = ((const float4*)x)[idx];
        unsigned n0 = (v.x >= 0.f) ? 0x2u : 0xAu;
        unsigned n1 = (v.y >= 0.f) ? 0x2u : 0xAu;
        unsigned n2 = (v.z >= 0.f) ? 0x2u : 0xAu;
        unsigned n3 = (v.w >= 0.f) ? 0x2u : 0xAu;
        xq[idx] = (unsigned short)(n0 | (n1 << 4) | (n2 << 8) | (n3 << 12));
        return;
    }

    // ---- k path: [D][U] f32 -> [U][D/2] fp4 transposed via 64x64 LDS tile ----
    const int bid = blockIdx.x;
    const int j0 = (bid & 31) * 64;   // U tile
    const int d0 = (bid >> 5) * 64;   // D tile
    const int lane = tid & 63;
    const int wv = tid >> 6;
    for (int i = 0; i < 16; i++) {
        int row = i * 4 + wv;
        tile[row][lane] = k[(size_t)(d0 + row) * U_DIM + j0 + lane];
    }
    __syncthreads();
    const int u = tid >> 2;          // 0..63 output row (unit)
    const int q = tid & 3;           // 8-byte group along D (16 elems)
    unsigned long long ob = 0ull;
#pragma unroll
    for (int jj = 0; jj < 8; ++jj) {
        float lo = tile[q * 16 + 2 * jj][u];
        float hi = tile[q * 16 + 2 * jj + 1][u];
        unsigned byte = ((lo >= 0.f) ? 0x2u : 0xAu) | (((hi >= 0.f) ? 0x2u : 0xAu) << 4);
        ob |= (unsigned long long)byte << (8 * jj);
    }
    *(unsigned long long*)(ktq + (size_t)(j0 + u) * DB + (d0 >> 1) + q * 8) = ob;
}

// out[i][j] = sum_k sign(x)*sign(k) + bias[j], exact in f32 via fp4 MFMA.
//
// R10 structure (proven: total 159.7 -> 144.7us, absmax 0): R3's measured-best
// 2-phase schedule with MX-fp4 operands - half the tiles (16 vs 32) at the
// same ~2650 cy/tile structural cost, 2.07x MFMA rate, half staging bytes.
// Per K-tile (BK=128 fp4 elems = 64B/row): per wave 12 ds_read_b128 +
// 16 mfma_scale_f32_32x32x64_f8f6f4; 2 phases; counted vmcnt(8); 4-deep ring.
//
// Bank swizzle folded into the GLOBAL source (LDS dest stays linear for
// global_load_lds): within each 128B row-pair, 16B slot s <- s ^ (pair&7).
// Grid = 256 blocks = 1/CU; XCD swizzle: contiguous 32-block chunk per XCD.
__launch_bounds__(512, 2)
__global__ void gemm_fp4(const char* __restrict__ xq,   // [8192][1024]
                         const char* __restrict__ ktq,  // [2048][1024]
                         const float* __restrict__ bias,
                         float* __restrict__ out) {
    __shared__ uint4 lds[4][2048];   // [buf][ A:slots 0..1023 | B:1024..2047 ]

    const int tid  = threadIdx.x;
    const int lane = tid & 63;
    const int w    = tid >> 6;       // 8 waves
    const int m    = lane & 31;
    const int half = lane >> 5;

    // XCD-aware swizzle (nwg=256, 8 XCDs, 32 blocks/chunk; bijective)
    const int bid = blockIdx.x;
    const int swz = ((bid & 7) << 5) | (bid >> 3);
    const int bx  = swz & 7;         // U tile index [0,8)
    const int by  = swz >> 3;        // B tile index [0,32)
    const int rows0 = by << 8;
    const int cols0 = bx << 8;

    const int wr = (w >> 2) << 7;    // wave row offset: 0 or 128
    const int wc = (w & 3) << 6;     // wave col offset: 0/64/128/192

    v16f acc[4][2];
#pragma unroll
    for (int mi = 0; mi < 4; ++mi)
#pragma unroll
        for (int nj = 0; nj < 2; ++nj)
#pragma unroll
            for (int i = 0; i < 16; ++i) acc[mi][nj][i] = 0.0f;

    const char* abase = xq  + (size_t)rows0 * DB;
    const char* bbase = ktq + (size_t)cols0 * DB;

    // --- staging precompute: 2 A-slots + 2 B-slots per thread ---
    // flat slot s in [0,1024): row = s>>2, g = s&3 (16B groups of 64B rows).
    // Storage slot (p=row>>1, sp=((row&1)<<2)|g) holds global slot
    // sl = sp ^ (p&7) -> row/group (swizzle folded into global source).
    int   sbase[2];
    size_t goff0[2];
#pragma unroll
    for (int j = 0; j < 2; ++j) {
        sbase[j] = (w << 6) + (j << 9);          // wave-uniform LDS slot base
        const int s   = sbase[j] + lane;
        const int row = s >> 2, g = s & 3;
        const int p   = row >> 1;
        const int sl  = ((((row & 1) << 2) | g) ^ (p & 7));
        const int gr  = (p << 1) | (sl >> 2);
        const int gg  = sl & 3;
        goff0[j] = (size_t)gr * DB + (size_t)(gg << 4);
    }

    auto stageA = [&](int t, int buf) {
        const size_t kof = (size_t)t << 6;       // t * 64 bytes along K
#pragma unroll
        for (int j = 0; j < 2; ++j)
            load_lds16(abase + goff0[j] + kof, (char*)&lds[buf][sbase[j]]);
    };
    auto stageB = [&](int t, int buf) {
        const size_t kof = (size_t)t << 6;
#pragma unroll
        for (int j = 0; j < 2; ++j)
            load_lds16(bbase + goff0[j] + kof, (char*)&lds[buf][1024 + sbase[j]]);
    };

    // --- fragment read offsets (loop-invariant; swizzled) ---
    // logical: row rl, 16B group gl = kk*2+half -> byte (rl>>1)*128 + st*16
    // (A/B use identical k-layouts -> within-lane permutation cancels.)
    int aoff[4][2], boff[2][2];
#pragma unroll
    for (int mi = 0; mi < 4; ++mi)
#pragma unroll
        for (int kk = 0; kk < 2; ++kk) {
            const int rl = wr + mi * 32 + m;
            const int gl = kk * 2 + half;
            const int p  = rl >> 1;
            const int st = ((((rl & 1) << 2) | gl) ^ (p & 7));
            aoff[mi][kk] = (p << 7) + (st << 4);
        }
#pragma unroll
    for (int nj = 0; nj < 2; ++nj)
#pragma unroll
        for (int kk = 0; kk < 2; ++kk) {
            const int rl = wc + nj * 32 + m;
            const int gl = kk * 2 + half;
            const int p  = rl >> 1;
            const int st = ((((rl & 1) << 2) | gl) ^ (p & 7));
            boff[nj][kk] = 16384 + (p << 7) + (st << 4);
        }

    // fp4 operands occupy the LOW 4 regs of the v8i MFMA operand.
    typedef union { v8i v8; v4i v4[2]; } opnd_t;

    auto phaseReads = [&](const char* Ls, int kk, opnd_t af[4], opnd_t bf[2]) {
#pragma unroll
        for (int mi = 0; mi < 4; ++mi) {
            af[mi].v4[1] = (v4i){0, 0, 0, 0};
            af[mi].v4[0] = *(const v4i*)(Ls + aoff[mi][kk]);
        }
#pragma unroll
        for (int nj = 0; nj < 2; ++nj) {
            bf[nj].v4[1] = (v4i){0, 0, 0, 0};
            bf[nj].v4[0] = *(const v4i*)(Ls + boff[nj][kk]);
        }
    };
    auto phaseMMA = [&](opnd_t af[4], opnd_t bf[2]) {
        __builtin_amdgcn_s_setprio(1);
#pragma unroll
        for (int mi = 0; mi < 4; ++mi)
#pragma unroll
            for (int nj = 0; nj < 2; ++nj)
                acc[mi][nj] = __builtin_amdgcn_mfma_scale_f32_32x32x64_f8f6f4(
                    af[mi].v8, bf[nj].v8, acc[mi][nj],
                    4, 4,                       // cbsz=FP4, blgp=FP4
                    0, 0x7F7F7F7Fu,             // scale_a = 1.0 (E8M0 127)
                    0, 0x7F7F7F7Fu);            // scale_b = 1.0
        __builtin_amdgcn_s_setprio(0);
    };

    // prologue: stage tiles 0,1,2 (12 loads/thread in flight)
    stageA(0, 0); stageB(0, 0);
    stageA(1, 1); stageB(1, 1);
    stageA(2, 2); stageB(2, 2);
    WAITVM(8);                        // tile 0 landed (own)
    SBAR;                             // ... chip-wide

    // main loop: tiles 0..12; stage tile t+3 into buf[(t+3)&3]
#pragma unroll 1
    for (int t = 0; t < 13; ++t) {
        const char* Ls = (const char*)lds[t & 3];
        const int nb = (t + 3) & 3;
        opnd_t af[4], bf[2];
        // ---- phase A (kk=0) ----
        phaseReads(Ls, 0, af, bf);
        stageA(t + 3, nb);
        SCHED0; SBAR; LGKM0;
        phaseMMA(af, bf);
        SBAR;
        // ---- phase B (kk=1) ----
        phaseReads(Ls, 1, af, bf);
        stageB(t + 3, nb);
        WAITVM(8);                    // tile t+1 landed (own); barrier -> all
        SCHED0; SBAR; LGKM0;
        phaseMMA(af, bf);
        SBAR;
    }
    // peeled t=13 (buf 1): no staging; drain 8 -> 4
    {
        const char* Ls = (const char*)lds[1];
        opnd_t af[4], bf[2];
        phaseReads(Ls, 0, af, bf);
        SCHED0; SBAR; LGKM0; phaseMMA(af, bf); SBAR;
        phaseReads(Ls, 1, af, bf);
        WAITVM(4);                    // tile 14 landed
        SCHED0; SBAR; LGKM0; phaseMMA(af, bf); SBAR;
    }
    // peeled t=14 (buf 2): drain 4 -> 0
    {
        const char* Ls = (const char*)lds[2];
        opnd_t af[4], bf[2];
        phaseReads(Ls, 0, af, bf);
        SCHED0; SBAR; LGKM0; phaseMMA(af, bf); SBAR;
        phaseReads(Ls, 1, af, bf);
        WAITVM(0);                    // tile 15 landed
        SCHED0; SBAR; LGKM0; phaseMMA(af, bf); SBAR;
    }
    // peeled t=15 (buf 3): everything resident
    {
        const char* Ls = (const char*)lds[3];
        opnd_t af[4], bf[2];
        phaseReads(Ls, 0, af, bf);
        phaseMMA(af, bf);
        phaseReads(Ls, 1, af, bf);
        phaseMMA(af, bf);
    }

    // C/D 32x32 layout (HW-verified, shape-determined not dtype-determined):
    // col = lane&31, row = (reg&3)+8*(reg>>2)+4*half. acc is already f32.
#pragma unroll
    for (int mi = 0; mi < 4; ++mi)
#pragma unroll
        for (int nj = 0; nj < 2; ++nj) {
            const int n = cols0 + wc + nj * 32 + m;
            const float bb = bias[n];
#pragma unroll
            for (int reg = 0; reg < 16; ++reg) {
                const int row = (reg & 3) + 8 * (reg >> 2) + 4 * half;
                const size_t grow = (size_t)(rows0 + wr + mi * 32 + row);
                out[grow * U_DIM + n] = acc[mi][nj][reg] + bb;
            }
        }
}

// ======================= BIT-PATH FALLBACK (R5, proven) =======================

__global__ void pack_x_kernel(const float* __restrict__ x,
                              unsigned long long* __restrict__ xb) {
    const int gwave = (blockIdx.x * blockDim.x + threadIdx.x) >> 6;
    const int lane  = threadIdx.x & 63;
    const size_t base = (size_t)gwave * 256;
    float v0 = x[base + lane];
    float v1 = x[base + 64 + lane];
    float v2 = x[base + 128 + lane];
    float v3 = x[base + 192 + lane];
    unsigned long long m0 = __ballot(v0 >= 0.0f);
    unsigned long long m1 = __ballot(v1 >= 0.0f);
    unsigned long long m2 = __ballot(v2 >= 0.0f);
    unsigned long long m3 = __ballot(v3 >= 0.0f);
    if (lane == 0) {
        ulonglong2* p = (ulonglong2*)(xb + (base >> 6));
        ulonglong2 a; a.x = m0; a.y = m1;
        ulonglong2 b; b.x = m2; b.y = m3;
        p[0] = a;
        p[1] = b;
    }
}

__global__ void pack_k_kernel(const float* __restrict__ k,
                              unsigned long long* __restrict__ kb) {
    __shared__ float tile[64][65];
    const int j0 = (blockIdx.x & 31) * 64;
    const int d0 = (blockIdx.x >> 5) * 64;
    const int tid  = threadIdx.x;
    const int lane = tid & 63;
    const int wv   = tid >> 6;
    for (int i = 0; i < 16; i++) {
        int row = i * 4 + wv;
        tile[row][lane] = k[(size_t)(d0 + row) * U_DIM + j0 + lane];
    }
    __syncthreads();
    for (int c = wv * 16; c < wv * 16 + 16; c++) {
        float v = tile[lane][c];
        unsigned long long m = __ballot(v >= 0.0f);
        if (lane == 0) kb[(size_t)(j0 + c) * (D_DIM / 64) + (d0 >> 6)] = m;
    }
}

__launch_bounds__(512)
__global__ void bgemm_kernel(const unsigned int* __restrict__ xb,
                             const unsigned int* __restrict__ kb,
                             const float* __restrict__ bias,
                             float* __restrict__ out) {
    __shared__ unsigned int xs[128 * KWORDS];
    __shared__ unsigned int ks[128 * KWORDS];
    const int bx  = blockIdx.x;
    const int by  = blockIdx.y;
    const int tid = threadIdx.x;
    const uint4* xsrc = (const uint4*)(xb + (size_t)(by * 128) * KWORDS);
    const uint4* ksrc = (const uint4*)(kb + (size_t)(bx * 128) * KWORDS);
#pragma unroll
    for (int i = 0; i < 4; i++) {
        int flat = tid + i * 512;
        int r    = flat >> 4;
        int g    = flat & 15;
        int sg   = g ^ ((r >> 3) & 7);
        uint4 xv = xsrc[flat];
        uint4 kv = ksrc[flat];
        *((uint4*)&xs[r * KWORDS + sg * 4]) = xv;
        *((uint4*)&ks[r * KWORDS + sg * 4]) = kv;
    }
    __syncthreads();
    const int tr   = (tid >> 4) * 4;
    const int tc   = (tid & 15) * 8;
    const int xswz = ((tid >> 4) >> 1) & 7;
    const int ksw  = tid & 7;
    int acc[4][8] = {};
    for (int w4 = 0; w4 < 16; w4++) {
        const int xcol = (w4 ^ xswz) * 4;
        const int kcol = (w4 ^ ksw) * 4;
        uint4 xv[4], kv[8];
#pragma unroll
        for (int r = 0; r < 4; r++) xv[r] = *((const uint4*)&xs[(tr + r) * KWORDS + xcol]);
#pragma unroll
        for (int c = 0; c < 8; c++) kv[c] = *((const uint4*)&ks[(tc + c) * KWORDS + kcol]);
#pragma unroll
        for (int r = 0; r < 4; r++)
#pragma unroll
            for (int c = 0; c < 8; c++) {
                acc[r][c] += __popc(xv[r].x ^ kv[c].x);
                acc[r][c] += __popc(xv[r].y ^ kv[c].y);
                acc[r][c] += __popc(xv[r].z ^ kv[c].z);
                acc[r][c] += __popc(xv[r].w ^ kv[c].w);
            }
    }
    const int row0 = by * 128 + tr;
    const int col0 = bx * 128 + tc;
    const float4 b0 = *((const float4*)&bias[col0]);
    const float4 b1 = *((const float4*)&bias[col0 + 4]);
#pragma unroll
    for (int r = 0; r < 4; r++) {
        float4 o0, o1;
        o0.x = (float)(D_DIM - 2 * acc[r][0]) + b0.x;
        o0.y = (float)(D_DIM - 2 * acc[r][1]) + b0.y;
        o0.z = (float)(D_DIM - 2 * acc[r][2]) + b0.z;
        o0.w = (float)(D_DIM - 2 * acc[r][3]) + b0.w;
        o1.x = (float)(D_DIM - 2 * acc[r][4]) + b1.x;
        o1.y = (float)(D_DIM - 2 * acc[r][5]) + b1.y;
        o1.z = (float)(D_DIM - 2 * acc[r][6]) + b1.z;
        o1.w = (float)(D_DIM - 2 * acc[r][7]) + b1.w;
        float* orow = &out[(size_t)(row0 + r) * U_DIM + col0];
        *((float4*)orow)       = o0;
        *((float4*)(orow + 4)) = o1;
    }
}

// ======================= launcher =======================

extern "C" void kernel_launch(void* const* d_in, const int* in_sizes, int n_in,
                              void* d_out, int out_size, void* d_ws, size_t ws_size,
                              hipStream_t stream) {
    const float* x    = (const float*)d_in[0];   // [8192][2048]
    const float* k    = (const float*)d_in[1];   // [2048][2048]
    const float* bias = (const float*)d_in[2];   // [2048]
    float* out = (float*)d_out;

    const size_t need_fp4 = (size_t)B_DIM * DB + (size_t)U_DIM * DB; // ~10 MB
    if (ws_size >= need_fp4) {
        unsigned short* xq = (unsigned short*)d_ws;                  // 8 MB
        unsigned char*  ktq = (unsigned char*)d_ws + (size_t)B_DIM * DB; // 2 MB
        // single pack dispatch: 1024 kt-blocks + 16384 x-blocks
        pack_fp4<<<1024 + (B_DIM * D_DIM) / 1024, 256, 0, stream>>>(x, k, xq, ktq);
        gemm_fp4<<<256, 512, 0, stream>>>((const char*)xq, (const char*)ktq, bias, out);
    } else {
        unsigned long long* xbits = (unsigned long long*)d_ws;
        unsigned long long* kbits = (unsigned long long*)((char*)d_ws + (size_t)B_DIM * (D_DIM / 8));
        pack_x_kernel<<<(B_DIM * D_DIM) / 1024, 256, 0, stream>>>(x, xbits);
        pack_k_kernel<<<32 * 32, 256, 0, stream>>>(k, kbits);
        dim3 grid(U_DIM / 128, B_DIM / 128);
        bgemm_kernel<<<grid, 512, 0, stream>>>((const unsigned int*)xbits,
                                               (const unsigned int*)kbits, bias, out);
    }
}